// Round 6
// baseline (330.235 us; speedup 1.0000x reference)
//
#include <hip/hip_runtime.h>
#include <cstddef>

static constexpr int NN = 100000;   // nodes
static constexpr int NE = 1600000;  // edges
static constexpr int NODE_SHIFT = 8;                       // 256 nodes per bucket
static constexpr int NB = (NN + 255) >> NODE_SHIFT;        // 391 buckets
static constexpr int CHUNK = 8192;                         // edges per binning block
static constexpr int NCH = (NE + CHUNK - 1) / CHUNK;       // 196 chunks
static constexpr int NHALF = NN / 2;                       // 50000

typedef _Float16 f16x8 __attribute__((ext_vector_type(8)));
typedef float f32x4  __attribute__((ext_vector_type(4)));

// accumulate 8 packed f16 (uint4) into a[0..8)
__device__ __forceinline__ void acc8h(const uint4& v, float* a) {
    union { uint4 u; _Float16 h[8]; } t; t.u = v;
#pragma unroll
    for (int j = 0; j < 8; j++) a[j] += (float)t.h[j];
}

// ---------------- bucketed CSR construction ----------------

__global__ void bucket_count(const int* __restrict__ eidx, int* __restrict__ bcnt) {
    __shared__ int h[NB];
    for (int i = threadIdx.x; i < NB; i += 256) h[i] = 0;
    __syncthreads();
    int base = blockIdx.x * CHUNK;
    int end = min(base + CHUNK, NE);
    for (int e = base + threadIdx.x; e < end; e += 256)
        atomicAdd(&h[eidx[NE + e] >> NODE_SHIFT], 1);
    __syncthreads();
    for (int i = threadIdx.x; i < NB; i += 256)
        if (h[i]) atomicAdd(&bcnt[i], h[i]);
}

__global__ void bucket_scan(const int* __restrict__ bcnt, int* __restrict__ bbase,
                            int* __restrict__ bcur, int* __restrict__ row_ptr) {
    __shared__ int s[512];
    int t = threadIdx.x;
    int v = (t < NB) ? bcnt[t] : 0;
    s[t] = v; __syncthreads();
    for (int off = 1; off < 512; off <<= 1) {
        int x = (t >= off) ? s[t - off] : 0;
        __syncthreads();
        s[t] += x;
        __syncthreads();
    }
    if (t < NB) { int e = s[t] - v; bbase[t] = e; bcur[t] = e; }
    if (t == 0) { bbase[NB] = NE; row_ptr[NN] = NE; }
}

__global__ void bucket_scatter(const int* __restrict__ eidx, int* __restrict__ bcur,
                               uint2* __restrict__ pairs) {
    __shared__ int h[NB];
    __shared__ int cur[NB];
    __shared__ int off[NB];
    for (int i = threadIdx.x; i < NB; i += 256) { h[i] = 0; cur[i] = 0; }
    __syncthreads();
    int base = blockIdx.x * CHUNK;
    int end = min(base + CHUNK, NE);
    for (int e = base + threadIdx.x; e < end; e += 256)
        atomicAdd(&h[eidx[NE + e] >> NODE_SHIFT], 1);
    __syncthreads();
    for (int i = threadIdx.x; i < NB; i += 256)
        off[i] = h[i] ? atomicAdd(&bcur[i], h[i]) : 0;
    __syncthreads();
    for (int e = base + threadIdx.x; e < end; e += 256) {
        int d = eidx[NE + e], s = eidx[e];
        int b = d >> NODE_SHIFT;
        int p = atomicAdd(&cur[b], 1);
        pairs[off[b] + p] = make_uint2((unsigned)s, (unsigned)d);
    }
}

__launch_bounds__(256)
__global__ void bucket_csr(const uint2* __restrict__ pairs, const int* __restrict__ bbase,
                           int* __restrict__ row_ptr, int* __restrict__ ecsr) {
    __shared__ int hist[256];
    __shared__ int scn[256];
    __shared__ int cur[256];
    int b = blockIdx.x, t = threadIdx.x;
    int ebeg = bbase[b], eend = bbase[b + 1];
    int node0 = b << NODE_SHIFT;
    hist[t] = 0;
    __syncthreads();
    for (int e = ebeg + t; e < eend; e += 256)
        atomicAdd(&hist[pairs[e].y & 255u], 1);
    __syncthreads();
    int v = hist[t];
    scn[t] = v; __syncthreads();
    for (int off = 1; off < 256; off <<= 1) {
        int x = (t >= off) ? scn[t - off] : 0;
        __syncthreads();
        scn[t] += x;
        __syncthreads();
    }
    int excl = scn[t] - v;
    int node = node0 + t;
    if (node < NN) row_ptr[node] = ebeg + excl;
    cur[t] = excl;
    __syncthreads();
    for (int e = ebeg + t; e < eend; e += 256) {
        uint2 pr = pairs[e];
        int p = atomicAdd(&cur[pr.y & 255u], 1);
        ecsr[ebeg + p] = (int)pr.x;
    }
}

// ---------------- fused conversions + bcnt zeroing (one launch) ----------------
__global__ void conv_fused(const float* __restrict__ x,
                           const float* __restrict__ W1l, const float* __restrict__ W1r,
                           const float* __restrict__ Wlin1, const float* __restrict__ W2l,
                           const float* __restrict__ W2r, const float* __restrict__ Wlin2,
                           unsigned short* __restrict__ bufP, unsigned short* __restrict__ Wt1,
                           unsigned short* __restrict__ Wtl1, unsigned short* __restrict__ Wt2,
                           unsigned short* __restrict__ Wtf, int* __restrict__ bcnt) {
    int bid = blockIdx.x, t = threadIdx.x;
    union { _Float16 h; unsigned short u; } cv;
    if (bid < 25000) {
        int idx = bid * 256 + t;               // < NN*64 = 6.4M exactly
        int r = idx >> 6, c = idx & 63;
        cv.h = (_Float16)x[idx];
        bufP[(size_t)r * 128 + 64 + c] = cv.u;
    } else if (bid >= 25288) {
        int i = (bid - 25288) * 256 + t;
        if (i < NB) bcnt[i] = 0;
    } else {
        int b = bid - 25000;
        const float* W; unsigned short* Wt; int K, C, wld, kbase, base;
        if (b < 32)       { W = W1l;   Wt = Wt1;  K = 64;  C = 128; wld = 128; kbase = 0;   base = b; }
        else if (b < 64)  { W = W1r;   Wt = Wt1;  K = 64;  C = 128; wld = 128; kbase = 64;  base = b - 32; }
        else if (b < 128) { W = Wlin1; Wt = Wtl1; K = 128; C = 128; wld = 128; kbase = 0;   base = b - 64; }
        else if (b < 192) { W = W2l;   Wt = Wt2;  K = 128; C = 128; wld = 256; kbase = 0;   base = b - 128; }
        else if (b < 256) { W = W2r;   Wt = Wt2;  K = 128; C = 128; wld = 256; kbase = 128; base = b - 192; }
        else              { W = Wlin2; Wt = Wtf;  K = 128; C = 64;  wld = 128; kbase = 0;   base = b - 256; }
        int idx = base * 256 + t;
        if (idx < K * C) {
            int k = idx / C, c = idx % C;
            cv.h = (_Float16)W[idx];
            Wt[(size_t)c * wld + kbase + k] = cv.u;
        }
    }
}

// ---------------- mean aggregation (f16 gather, 16B/lane, x4 unroll) ----------------
// Rounds 12-14: rebalance and deeper MLP both failed; this x4 / 4-acc / VGPR-40
// form is the measured optimum (gather sits at the random-granule service floor).
// Round-15: DIAGNOSTIC split into half-range dispatches (template<HALF>) so the
// top-5 profile view reveals the next tier of dispatches below agg2 (~150us of
// the 315us budget is currently invisible). Work is bit-identical.

// layer 1: gather f16 x rows (bufP cols [64,128), 128B), mean -> bufP cols [0,64)
template<int HALF>
__launch_bounds__(256)
__global__ void agg1_t(const unsigned short* __restrict__ xp, const int* __restrict__ row_ptr,
                       const int* __restrict__ ecsr, unsigned short* __restrict__ outp) {
    constexpr int TPN = 8;
    constexpr int NODE0 = HALF * NHALF;
    constexpr int NODE1 = (HALF == 0) ? NHALF : NN;
    int node = NODE0 + blockIdx.x * (256 / TPN) + threadIdx.x / TPN;
    int lane = threadIdx.x % TPN;
    if (node >= NODE1) return;
    int beg = row_ptr[node], end = row_ptr[node + 1];

    float a0[8] = {0,0,0,0,0,0,0,0}, a1[8] = {0,0,0,0,0,0,0,0};
    float a2[8] = {0,0,0,0,0,0,0,0}, a3[8] = {0,0,0,0,0,0,0,0};
    int i = beg;
    for (; i + 4 <= end; i += 4) {
        int s0 = ecsr[i], s1 = ecsr[i + 1], s2 = ecsr[i + 2], s3 = ecsr[i + 3];
        uint4 v0 = *(const uint4*)&xp[(size_t)s0 * 128 + 64 + lane * 8];
        uint4 v1 = *(const uint4*)&xp[(size_t)s1 * 128 + 64 + lane * 8];
        uint4 v2 = *(const uint4*)&xp[(size_t)s2 * 128 + 64 + lane * 8];
        uint4 v3 = *(const uint4*)&xp[(size_t)s3 * 128 + 64 + lane * 8];
        acc8h(v0, a0); acc8h(v1, a1); acc8h(v2, a2); acc8h(v3, a3);
    }
    for (; i < end; i++) {
        uint4 v0 = *(const uint4*)&xp[(size_t)ecsr[i] * 128 + 64 + lane * 8];
        acc8h(v0, a0);
    }
    int deg = end - beg;
    float r = (deg > 0) ? 1.f / (float)deg : 0.f;
    union { uint4 u; _Float16 h[8]; } o;
#pragma unroll
    for (int j = 0; j < 8; j++)
        o.h[j] = (_Float16)((a0[j] + a1[j] + a2[j] + a3[j]) * r);
    *(uint4*)(outp + (size_t)node * 128 + lane * 8) = o.u;
}

// layer 2: gather f16 h rows (bufQ cols [128,256), 256B), mean -> bufQ cols [0,128)
template<int HALF>
__launch_bounds__(256)
__global__ void agg2_t(const unsigned short* __restrict__ hbuf, const int* __restrict__ row_ptr,
                       const int* __restrict__ ecsr, unsigned short* __restrict__ outp) {
    constexpr int TPN = 16;
    constexpr int NODE0 = HALF * NHALF;
    constexpr int NODE1 = (HALF == 0) ? NHALF : NN;
    int node = NODE0 + blockIdx.x * (256 / TPN) + threadIdx.x / TPN;
    int lane = threadIdx.x % TPN;
    if (node >= NODE1) return;
    int beg = row_ptr[node], end = row_ptr[node + 1];

    float a0[8] = {0,0,0,0,0,0,0,0}, a1[8] = {0,0,0,0,0,0,0,0};
    float a2[8] = {0,0,0,0,0,0,0,0}, a3[8] = {0,0,0,0,0,0,0,0};
    int i = beg;
    for (; i + 4 <= end; i += 4) {
        int s0 = ecsr[i], s1 = ecsr[i + 1], s2 = ecsr[i + 2], s3 = ecsr[i + 3];
        uint4 v0 = *(const uint4*)&hbuf[(size_t)s0 * 256 + 128 + lane * 8];
        uint4 v1 = *(const uint4*)&hbuf[(size_t)s1 * 256 + 128 + lane * 8];
        uint4 v2 = *(const uint4*)&hbuf[(size_t)s2 * 256 + 128 + lane * 8];
        uint4 v3 = *(const uint4*)&hbuf[(size_t)s3 * 256 + 128 + lane * 8];
        acc8h(v0, a0); acc8h(v1, a1); acc8h(v2, a2); acc8h(v3, a3);
    }
    for (; i < end; i++) {
        uint4 v0 = *(const uint4*)&hbuf[(size_t)ecsr[i] * 256 + 128 + lane * 8];
        acc8h(v0, a0);
    }
    int deg = end - beg;
    float r = (deg > 0) ? 1.f / (float)deg : 0.f;
    union { uint4 u; _Float16 h[8]; } o;
#pragma unroll
    for (int j = 0; j < 8; j++)
        o.h[j] = (_Float16)((a0[j] + a1[j] + a2[j] + a3[j]) * r);
    *(uint4*)(outp + (size_t)node * 256 + lane * 8) = o.u;
}

// ---------------- fused back-to-back f16 MFMA GEMM pair ----------------
// Round-11: GEMM-1 kept in LDS (Hs0|Hs1), GEMM-2 reads A from LDS. Neutral vs
// unfused (intermediates are LLC-resident; HBM arithmetic didn't apply) but
// kept: fewer launches, less workspace.
template<int K1, int C2, bool RELU2, bool F16OUT2>
__launch_bounds__(256, 2)
__global__ void gemm2x(const unsigned short* __restrict__ A, int lda,
                       const unsigned short* __restrict__ Wta,
                       const float* __restrict__ ba,
                       const unsigned short* __restrict__ Wtb,
                       const float* __restrict__ bb,
                       unsigned short* __restrict__ outp, int old_, int obase,
                       float* __restrict__ outf) {
    constexpr int BM   = 128;
    constexpr int NKC1 = K1 / 64;
    __shared__ unsigned short As[BM * 72];
    __shared__ unsigned short Ws[128 * 72];   // weight chunk buffer, reused by both gemms
    __shared__ unsigned short Hs0[BM * 72];   // h tile, k in [0,64)
    __shared__ unsigned short Hs1[BM * 72];   // h tile, k in [64,128)

    const int tid  = threadIdx.x;
    const int lane = tid & 63, wave = tid >> 6;
    const int lrow = lane & 15, quad = lane >> 4;
    const int row0 = blockIdx.x * BM;

    // ---- GEMM-1 (C = 128 layout) ----
    const int wrow0 = (wave >> 1) * 64;
    const int wcol0 = (wave & 1) * 64;

    f32x4 acc[4][4];
#pragma unroll
    for (int a = 0; a < 4; a++)
#pragma unroll
        for (int b = 0; b < 4; b++) acc[a][b] = (f32x4){0.f, 0.f, 0.f, 0.f};

#pragma unroll 1
    for (int it = 0; it < NKC1; ++it) {
        int base = it * 64;
        for (int t = tid; t < BM * 8; t += 256) {
            int r = t >> 3, c8 = (t & 7) * 8;
            int gr = row0 + r;
            uint4 v = make_uint4(0u, 0u, 0u, 0u);
            if (gr < NN) v = *(const uint4*)&A[(size_t)gr * lda + base + c8];
            *(uint4*)&As[r * 72 + c8] = v;
        }
        for (int t = tid; t < 128 * 8; t += 256) {
            int wr = t >> 3, c8 = (t & 7) * 8;
            *(uint4*)&Ws[wr * 72 + c8] = *(const uint4*)&Wta[(size_t)wr * K1 + base + c8];
        }
        __syncthreads();
#pragma unroll
        for (int ks = 0; ks < 2; ++ks) {
            f16x8 af[4], bfr[4];
#pragma unroll
            for (int rt = 0; rt < 4; rt++)
                af[rt] = *(const f16x8*)&As[(wrow0 + rt * 16 + lrow) * 72 + ks * 32 + quad * 8];
#pragma unroll
            for (int ct = 0; ct < 4; ct++)
                bfr[ct] = *(const f16x8*)&Ws[(wcol0 + ct * 16 + lrow) * 72 + ks * 32 + quad * 8];
#pragma unroll
            for (int rt = 0; rt < 4; rt++)
#pragma unroll
                for (int ct = 0; ct < 4; ct++)
                    acc[rt][ct] = __builtin_amdgcn_mfma_f32_16x16x32_f16(
                        af[rt], bfr[ct], acc[rt][ct], 0, 0, 0);
        }
        __syncthreads();
    }

    // ---- epilogue-1: bias+relu, f16 -> Hs (C/D layout: col=lane&15, row=quad*4+reg) ----
    {
        unsigned short* Hp = (wcol0 == 0) ? Hs0 : Hs1;
        float bc[4];
#pragma unroll
        for (int ct = 0; ct < 4; ct++) bc[ct] = ba[wcol0 + ct * 16 + lrow];
#pragma unroll
        for (int rt = 0; rt < 4; rt++) {
#pragma unroll
            for (int ct = 0; ct < 4; ct++) {
#pragma unroll
                for (int r = 0; r < 4; r++) {
                    int rl = wrow0 + rt * 16 + quad * 4 + r;    // local row, always valid
                    float v = fmaxf(acc[rt][ct][r] + bc[ct], 0.f);
                    union { _Float16 h; unsigned short u; } cv;
                    cv.h = (_Float16)v;
                    Hp[rl * 72 + ct * 16 + lrow] = cv.u;        // finite for OOB rows (A zero-padded)
                }
            }
        }
    }

    // ---- GEMM-2: [BM x 128] @ Wtb -> C2 ----
    constexpr int RT2 = (C2 == 128) ? 4 : 2;
    const int wrow2 = (C2 == 128) ? (wave >> 1) * 64 : wave * 32;
    const int wcol2 = (C2 == 128) ? (wave & 1) * 64 : 0;

    f32x4 acc2[RT2][4];
#pragma unroll
    for (int a = 0; a < RT2; a++)
#pragma unroll
        for (int b = 0; b < 4; b++) acc2[a][b] = (f32x4){0.f, 0.f, 0.f, 0.f};

#pragma unroll
    for (int it = 0; it < 2; ++it) {
        const unsigned short* Hp = it ? Hs1 : Hs0;
        for (int t = tid; t < C2 * 8; t += 256) {
            int wr = t >> 3, c8 = (t & 7) * 8;
            *(uint4*)&Ws[wr * 72 + c8] = *(const uint4*)&Wtb[(size_t)wr * 128 + it * 64 + c8];
        }
        __syncthreads();   // makes Hs writes + Ws chunk visible to all waves
#pragma unroll
        for (int ks = 0; ks < 2; ++ks) {
            f16x8 af[RT2], bfr[4];
#pragma unroll
            for (int rt = 0; rt < RT2; rt++)
                af[rt] = *(const f16x8*)&Hp[(wrow2 + rt * 16 + lrow) * 72 + ks * 32 + quad * 8];
#pragma unroll
            for (int ct = 0; ct < 4; ct++)
                bfr[ct] = *(const f16x8*)&Ws[(wcol2 + ct * 16 + lrow) * 72 + ks * 32 + quad * 8];
#pragma unroll
            for (int rt = 0; rt < RT2; rt++)
#pragma unroll
                for (int ct = 0; ct < 4; ct++)
                    acc2[rt][ct] = __builtin_amdgcn_mfma_f32_16x16x32_f16(
                        af[rt], bfr[ct], acc2[rt][ct], 0, 0, 0);
        }
        __syncthreads();   // protect Ws before it=1 restage
    }

    // ---- epilogue-2 ----
    float bc2[4];
#pragma unroll
    for (int ct = 0; ct < 4; ct++) bc2[ct] = bb[wcol2 + ct * 16 + lrow];
#pragma unroll
    for (int rt = 0; rt < RT2; rt++) {
#pragma unroll
        for (int ct = 0; ct < 4; ct++) {
#pragma unroll
            for (int r = 0; r < 4; r++) {
                int grow = row0 + wrow2 + rt * 16 + quad * 4 + r;
                if (grow < NN) {
                    int col = wcol2 + ct * 16 + lrow;
                    float v = acc2[rt][ct][r] + bc2[ct];
                    if (RELU2) v = fmaxf(v, 0.f);
                    if (F16OUT2) {
                        union { _Float16 h; unsigned short u; } cv;
                        cv.h = (_Float16)v;
                        outp[(size_t)grow * old_ + obase + col] = cv.u;
                    } else {
                        outf[(size_t)grow * C2 + col] = v;
                    }
                }
            }
        }
    }
}

// ---------------- launch ----------------

extern "C" void kernel_launch(void* const* d_in, const int* in_sizes, int n_in,
                              void* d_out, int out_size, void* d_ws, size_t ws_size,
                              hipStream_t stream) {
    const float* x     = (const float*)d_in[0];
    const int*   eidx  = (const int*)d_in[1];
    const float* W1l   = (const float*)d_in[2];
    const float* b1    = (const float*)d_in[3];
    const float* W1r   = (const float*)d_in[4];
    const float* Wlin1 = (const float*)d_in[5];
    const float* blin1 = (const float*)d_in[6];
    const float* W2l   = (const float*)d_in[7];
    const float* b2    = (const float*)d_in[8];
    const float* W2r   = (const float*)d_in[9];
    const float* Wlin2 = (const float*)d_in[10];
    const float* blin2 = (const float*)d_in[11];
    float* out = (float*)d_out;
    (void)in_sizes; (void)n_in; (void)out_size; (void)ws_size;

    char* ws = (char*)d_ws;
    size_t off = 0;
    auto alloc = [&](size_t bytes) -> void* {
        void* p = ws + off;
        off = (off + bytes + 255) & ~(size_t)255;
        return p;
    };
    int* bcnt    = (int*)alloc((size_t)NB * 4);
    int* bbase   = (int*)alloc((size_t)(NB + 1) * 4);
    int* bcur    = (int*)alloc((size_t)NB * 4);
    int* row_ptr = (int*)alloc((size_t)(NN + 1) * 4);
    int* ecsr    = (int*)alloc((size_t)NE * 4);
    uint2* pairs = (uint2*)alloc((size_t)NE * 8);
    unsigned short* Wt1  = (unsigned short*)alloc((size_t)128 * 128 * 2);  // [W1l|W1r]^T
    unsigned short* Wtl1 = (unsigned short*)alloc((size_t)128 * 128 * 2);  // Wlin1^T
    unsigned short* Wt2  = (unsigned short*)alloc((size_t)128 * 256 * 2);  // [W2l|W2r]^T
    unsigned short* Wtf  = (unsigned short*)alloc((size_t)64  * 128 * 2);  // Wlin2^T
    unsigned short* bufP = (unsigned short*)alloc((size_t)NN * 128 * 2);   // [mean1|x] f16
    unsigned short* bufQ = (unsigned short*)alloc((size_t)NN * 256 * 2);   // [mean2|h] f16

    // fused conversions + bcnt zeroing (1 launch replaces 8)
    conv_fused<<<25290, 256, 0, stream>>>(x, W1l, W1r, Wlin1, W2l, W2r, Wlin2,
                                          bufP, Wt1, Wtl1, Wt2, Wtf, bcnt);

    // bucketed CSR build
    bucket_count<<<NCH, 256, 0, stream>>>(eidx, bcnt);
    bucket_scan<<<1, 512, 0, stream>>>(bcnt, bbase, bcur, row_ptr);
    bucket_scatter<<<NCH, 256, 0, stream>>>(eidx, bcur, pairs);
    bucket_csr<<<NB, 256, 0, stream>>>(pairs, bbase, row_ptr, ecsr);

    // mean1 -> bufP cols 0..63 (split halves: diagnostic visibility)
    const int GA1 = (NHALF + 31) / 32;
    agg1_t<0><<<GA1, 256, 0, stream>>>(bufP, row_ptr, ecsr, bufP);
    agg1_t<1><<<GA1, 256, 0, stream>>>(bufP, row_ptr, ecsr, bufP);

    const int GB128 = (NN + 127) / 128;

    // fused L1: h1 = relu(bufP @ [W1l;W1r] + b1); h = relu(h1 @ Wlin1 + blin1)
    //           -> bufQ cols 128..255 (h1 never touches HBM)
    gemm2x<128, 128, true, true><<<GB128, 256, 0, stream>>>(
        bufP, 128, Wt1, b1, Wtl1, blin1, bufQ, 256, 128, nullptr);

    // mean2 from h -> bufQ cols 0..127 (split halves: diagnostic visibility)
    const int GA2 = (NHALF + 15) / 16;
    agg2_t<0><<<GA2, 256, 0, stream>>>(bufQ, row_ptr, ecsr, bufQ);
    agg2_t<1><<<GA2, 256, 0, stream>>>(bufQ, row_ptr, ecsr, bufQ);

    // fused L2: h2 = relu(bufQ @ [W2l;W2r] + b2); out = h2 @ Wlin2 + blin2 (fp32)
    gemm2x<256, 64, false, false><<<GB128, 256, 0, stream>>>(
        bufQ, 256, Wt2, b2, Wtf, blin2, nullptr, 0, 0, out);
}

// Round 7
// 317.415 us; speedup vs baseline: 1.0404x; 1.0404x over previous
//
#include <hip/hip_runtime.h>
#include <cstddef>

static constexpr int NN = 100000;   // nodes
static constexpr int NE = 1600000;  // edges
static constexpr int NODE_SHIFT = 8;                       // 256 nodes per bucket
static constexpr int NB = (NN + 255) >> NODE_SHIFT;        // 391 buckets
static constexpr int CHUNK = 8192;                         // edges per binning block
static constexpr int NCH = (NE + CHUNK - 1) / CHUNK;       // 196 chunks

typedef _Float16 f16x8 __attribute__((ext_vector_type(8)));
typedef float f32x4  __attribute__((ext_vector_type(4)));

// accumulate 8 packed f16 (uint4) into a[0..8)
__device__ __forceinline__ void acc8h(const uint4& v, float* a) {
    union { uint4 u; _Float16 h[8]; } t; t.u = v;
#pragma unroll
    for (int j = 0; j < 8; j++) a[j] += (float)t.h[j];
}

// ---------------- bucketed CSR construction ----------------

__global__ void bucket_count(const int* __restrict__ eidx, int* __restrict__ bcnt) {
    __shared__ int h[NB];
    for (int i = threadIdx.x; i < NB; i += 256) h[i] = 0;
    __syncthreads();
    int base = blockIdx.x * CHUNK;
    int end = min(base + CHUNK, NE);
    for (int e = base + threadIdx.x; e < end; e += 256)
        atomicAdd(&h[eidx[NE + e] >> NODE_SHIFT], 1);
    __syncthreads();
    for (int i = threadIdx.x; i < NB; i += 256)
        if (h[i]) atomicAdd(&bcnt[i], h[i]);
}

__global__ void bucket_scan(const int* __restrict__ bcnt, int* __restrict__ bbase,
                            int* __restrict__ bcur, int* __restrict__ row_ptr) {
    __shared__ int s[512];
    int t = threadIdx.x;
    int v = (t < NB) ? bcnt[t] : 0;
    s[t] = v; __syncthreads();
    for (int off = 1; off < 512; off <<= 1) {
        int x = (t >= off) ? s[t - off] : 0;
        __syncthreads();
        s[t] += x;
        __syncthreads();
    }
    if (t < NB) { int e = s[t] - v; bbase[t] = e; bcur[t] = e; }
    if (t == 0) { bbase[NB] = NE; row_ptr[NN] = NE; }
}

__global__ void bucket_scatter(const int* __restrict__ eidx, int* __restrict__ bcur,
                               uint2* __restrict__ pairs) {
    __shared__ int h[NB];
    __shared__ int cur[NB];
    __shared__ int off[NB];
    for (int i = threadIdx.x; i < NB; i += 256) { h[i] = 0; cur[i] = 0; }
    __syncthreads();
    int base = blockIdx.x * CHUNK;
    int end = min(base + CHUNK, NE);
    for (int e = base + threadIdx.x; e < end; e += 256)
        atomicAdd(&h[eidx[NE + e] >> NODE_SHIFT], 1);
    __syncthreads();
    for (int i = threadIdx.x; i < NB; i += 256)
        off[i] = h[i] ? atomicAdd(&bcur[i], h[i]) : 0;
    __syncthreads();
    for (int e = base + threadIdx.x; e < end; e += 256) {
        int d = eidx[NE + e], s = eidx[e];
        int b = d >> NODE_SHIFT;
        int p = atomicAdd(&cur[b], 1);
        pairs[off[b] + p] = make_uint2((unsigned)s, (unsigned)d);
    }
}

__launch_bounds__(256)
__global__ void bucket_csr(const uint2* __restrict__ pairs, const int* __restrict__ bbase,
                           int* __restrict__ row_ptr, int* __restrict__ ecsr) {
    __shared__ int hist[256];
    __shared__ int scn[256];
    __shared__ int cur[256];
    int b = blockIdx.x, t = threadIdx.x;
    int ebeg = bbase[b], eend = bbase[b + 1];
    int node0 = b << NODE_SHIFT;
    hist[t] = 0;
    __syncthreads();
    for (int e = ebeg + t; e < eend; e += 256)
        atomicAdd(&hist[pairs[e].y & 255u], 1);
    __syncthreads();
    int v = hist[t];
    scn[t] = v; __syncthreads();
    for (int off = 1; off < 256; off <<= 1) {
        int x = (t >= off) ? scn[t - off] : 0;
        __syncthreads();
        scn[t] += x;
        __syncthreads();
    }
    int excl = scn[t] - v;
    int node = node0 + t;
    if (node < NN) row_ptr[node] = ebeg + excl;
    cur[t] = excl;
    __syncthreads();
    for (int e = ebeg + t; e < eend; e += 256) {
        uint2 pr = pairs[e];
        int p = atomicAdd(&cur[pr.y & 255u], 1);
        ecsr[ebeg + p] = (int)pr.x;
    }
}

// ---------------- fused conversions + bcnt zeroing (one launch) ----------------
__global__ void conv_fused(const float* __restrict__ x,
                           const float* __restrict__ W1l, const float* __restrict__ W1r,
                           const float* __restrict__ Wlin1, const float* __restrict__ W2l,
                           const float* __restrict__ W2r, const float* __restrict__ Wlin2,
                           unsigned short* __restrict__ bufP, unsigned short* __restrict__ Wt1,
                           unsigned short* __restrict__ Wtl1, unsigned short* __restrict__ Wt2,
                           unsigned short* __restrict__ Wtf, int* __restrict__ bcnt) {
    int bid = blockIdx.x, t = threadIdx.x;
    union { _Float16 h; unsigned short u; } cv;
    if (bid < 25000) {
        int idx = bid * 256 + t;               // < NN*64 = 6.4M exactly
        int r = idx >> 6, c = idx & 63;
        cv.h = (_Float16)x[idx];
        bufP[(size_t)r * 128 + 64 + c] = cv.u;
    } else if (bid >= 25288) {
        int i = (bid - 25288) * 256 + t;
        if (i < NB) bcnt[i] = 0;
    } else {
        int b = bid - 25000;
        const float* W; unsigned short* Wt; int K, C, wld, kbase, base;
        if (b < 32)       { W = W1l;   Wt = Wt1;  K = 64;  C = 128; wld = 128; kbase = 0;   base = b; }
        else if (b < 64)  { W = W1r;   Wt = Wt1;  K = 64;  C = 128; wld = 128; kbase = 64;  base = b - 32; }
        else if (b < 128) { W = Wlin1; Wt = Wtl1; K = 128; C = 128; wld = 128; kbase = 0;   base = b - 64; }
        else if (b < 192) { W = W2l;   Wt = Wt2;  K = 128; C = 128; wld = 256; kbase = 0;   base = b - 128; }
        else if (b < 256) { W = W2r;   Wt = Wt2;  K = 128; C = 128; wld = 256; kbase = 128; base = b - 192; }
        else              { W = Wlin2; Wt = Wtf;  K = 128; C = 64;  wld = 128; kbase = 0;   base = b - 256; }
        int idx = base * 256 + t;
        if (idx < K * C) {
            int k = idx / C, c = idx % C;
            cv.h = (_Float16)W[idx];
            Wt[(size_t)c * wld + kbase + k] = cv.u;
        }
    }
}

// ---------------- generic f16 MFMA GEMM (round-9 structure, (256,4)) ----------------
template<int K, int C, bool RELU, bool F16OUT>
__launch_bounds__(256, 4)
__global__ void gemm_f16(const unsigned short* __restrict__ A, int lda,
                         const unsigned short* __restrict__ Wt,
                         const float* __restrict__ bias,
                         unsigned short* __restrict__ outp, int old_, int obase,
                         float* __restrict__ outf) {
    constexpr int BM  = 128;
    constexpr int NKC = K / 64;
    constexpr int RT  = (C == 128) ? 4 : 2;
    __shared__ unsigned short As[BM * 72];
    __shared__ unsigned short Ws[C * 72];

    const int tid  = threadIdx.x;
    const int lane = tid & 63, wave = tid >> 6;
    const int lrow = lane & 15, quad = lane >> 4;
    const int wrow0 = (C == 128) ? (wave >> 1) * 64 : wave * 32;
    const int wcol0 = (C == 128) ? (wave & 1) * 64 : 0;
    const int row0  = blockIdx.x * BM;

    f32x4 acc[RT][4];
#pragma unroll
    for (int a = 0; a < RT; a++)
#pragma unroll
        for (int b = 0; b < 4; b++) acc[a][b] = (f32x4){0.f, 0.f, 0.f, 0.f};

#pragma unroll 1
    for (int it = 0; it < NKC; ++it) {
        int base = it * 64;
        for (int t = tid; t < BM * 8; t += 256) {
            int r = t >> 3, c8 = (t & 7) * 8;
            int gr = row0 + r;
            uint4 v = make_uint4(0u, 0u, 0u, 0u);
            if (gr < NN) v = *(const uint4*)&A[(size_t)gr * lda + base + c8];
            *(uint4*)&As[r * 72 + c8] = v;
        }
        for (int t = tid; t < C * 8; t += 256) {
            int wr = t >> 3, c8 = (t & 7) * 8;
            *(uint4*)&Ws[wr * 72 + c8] = *(const uint4*)&Wt[(size_t)wr * K + base + c8];
        }
        __syncthreads();
#pragma unroll
        for (int ks = 0; ks < 2; ++ks) {
            f16x8 af[RT], bfr[4];
#pragma unroll
            for (int rt = 0; rt < RT; rt++)
                af[rt] = *(const f16x8*)&As[(wrow0 + rt * 16 + lrow) * 72 + ks * 32 + quad * 8];
#pragma unroll
            for (int ct = 0; ct < 4; ct++)
                bfr[ct] = *(const f16x8*)&Ws[(wcol0 + ct * 16 + lrow) * 72 + ks * 32 + quad * 8];
#pragma unroll
            for (int rt = 0; rt < RT; rt++)
#pragma unroll
                for (int ct = 0; ct < 4; ct++)
                    acc[rt][ct] = __builtin_amdgcn_mfma_f32_16x16x32_f16(
                        af[rt], bfr[ct], acc[rt][ct], 0, 0, 0);
        }
        __syncthreads();
    }

    // epilogue: C/D layout col=lane&15, row=quad*4+reg [m89/m91 verified]
    float bcol[4];
#pragma unroll
    for (int ct = 0; ct < 4; ct++) bcol[ct] = bias[wcol0 + ct * 16 + lrow];
#pragma unroll
    for (int rt = 0; rt < RT; rt++) {
#pragma unroll
        for (int ct = 0; ct < 4; ct++) {
#pragma unroll
            for (int r = 0; r < 4; r++) {
                int grow = row0 + wrow0 + rt * 16 + quad * 4 + r;
                if (grow < NN) {
                    int col = wcol0 + ct * 16 + lrow;
                    float v = acc[rt][ct][r] + bcol[ct];
                    if (RELU) v = fmaxf(v, 0.f);
                    if (F16OUT) {
                        union { _Float16 h; unsigned short u; } cv;
                        cv.h = (_Float16)v;
                        outp[(size_t)grow * old_ + obase + col] = cv.u;
                    } else {
                        outf[(size_t)grow * C + col] = v;
                    }
                }
            }
        }
    }
}

// ---------------- SAGE L1: fused mean1-gather + GEMM ----------------
// Round-16: each block's A-tile rows are exactly its own 128 output rows, so the
// block computes its own mean (no cross-block dep). TPN=8 lane mapping writes each
// uint4 mean fragment DIRECTLY into As[r*72 + l*8] == the it=0 K-chunk (cols 0..63)
// -- no global round-trip for mean1. x chunk (it=1) staged from bufP cols 64..127.
// (256,4): LDS 36.9KB -> 4 blocks/CU = 16 waves/CU during gather, matching the
// standalone agg occupancy (round-13/14: gathers live on wave parallelism).
__launch_bounds__(256, 4)
__global__ void gemm_s1(const unsigned short* __restrict__ xp,
                        const int* __restrict__ row_ptr, const int* __restrict__ ecsr,
                        const unsigned short* __restrict__ Wt,   // Wt1, wld=128, K=128
                        const float* __restrict__ bias,
                        unsigned short* __restrict__ outp) {     // bufR, 128 cols
    constexpr int BM = 128;
    __shared__ unsigned short As[BM * 72];
    __shared__ unsigned short Ws[128 * 72];

    const int tid  = threadIdx.x;
    const int lane = tid & 63, wave = tid >> 6;
    const int lrow = lane & 15, quad = lane >> 4;
    const int wrow0 = (wave >> 1) * 64;
    const int wcol0 = (wave & 1) * 64;
    const int row0  = blockIdx.x * BM;

    // ---- phase 1: mean1 for own rows -> As (it=0 chunk), x4/4-acc form ----
    {
        const int l = tid & 7;          // 8 lanes x 8 f16 = 64 cols
        const int rb = tid >> 3;        // 32 nodes per pass
#pragma unroll 1
        for (int p = 0; p < 4; p++) {
            int r = p * 32 + rb;
            int node = row0 + r;
            union { uint4 u; _Float16 h[8]; } o;
            if (node < NN) {
                int beg = row_ptr[node], end = row_ptr[node + 1];
                float a0[8] = {0,0,0,0,0,0,0,0}, a1[8] = {0,0,0,0,0,0,0,0};
                float a2[8] = {0,0,0,0,0,0,0,0}, a3[8] = {0,0,0,0,0,0,0,0};
                int i = beg;
                for (; i + 4 <= end; i += 4) {
                    int s0 = ecsr[i], s1 = ecsr[i + 1], s2 = ecsr[i + 2], s3 = ecsr[i + 3];
                    uint4 v0 = *(const uint4*)&xp[(size_t)s0 * 128 + 64 + l * 8];
                    uint4 v1 = *(const uint4*)&xp[(size_t)s1 * 128 + 64 + l * 8];
                    uint4 v2 = *(const uint4*)&xp[(size_t)s2 * 128 + 64 + l * 8];
                    uint4 v3 = *(const uint4*)&xp[(size_t)s3 * 128 + 64 + l * 8];
                    acc8h(v0, a0); acc8h(v1, a1); acc8h(v2, a2); acc8h(v3, a3);
                }
                for (; i < end; i++) {
                    uint4 v0 = *(const uint4*)&xp[(size_t)ecsr[i] * 128 + 64 + l * 8];
                    acc8h(v0, a0);
                }
                int deg = end - beg;
                float rr = (deg > 0) ? 1.f / (float)deg : 0.f;
#pragma unroll
                for (int j = 0; j < 8; j++)
                    o.h[j] = (_Float16)((a0[j] + a1[j] + a2[j] + a3[j]) * rr);
            } else {
                o.u = make_uint4(0u, 0u, 0u, 0u);
            }
            *(uint4*)&As[r * 72 + l * 8] = o.u;
        }
    }

    f32x4 acc[4][4];
#pragma unroll
    for (int a = 0; a < 4; a++)
#pragma unroll
        for (int b = 0; b < 4; b++) acc[a][b] = (f32x4){0.f, 0.f, 0.f, 0.f};

#pragma unroll 1
    for (int it = 0; it < 2; ++it) {
        int base = it * 64;
        if (it == 1) {
            // x chunk: A cols 64..127 == bufP cols 64..127
            for (int t = tid; t < BM * 8; t += 256) {
                int r = t >> 3, c8 = (t & 7) * 8;
                int gr = row0 + r;
                uint4 v = make_uint4(0u, 0u, 0u, 0u);
                if (gr < NN) v = *(const uint4*)&xp[(size_t)gr * 128 + 64 + c8];
                *(uint4*)&As[r * 72 + c8] = v;
            }
        }
        for (int t = tid; t < 128 * 8; t += 256) {
            int wr = t >> 3, c8 = (t & 7) * 8;
            *(uint4*)&Ws[wr * 72 + c8] = *(const uint4*)&Wt[(size_t)wr * 128 + base + c8];
        }
        __syncthreads();
#pragma unroll
        for (int ks = 0; ks < 2; ++ks) {
            f16x8 af[4], bfr[4];
#pragma unroll
            for (int rt = 0; rt < 4; rt++)
                af[rt] = *(const f16x8*)&As[(wrow0 + rt * 16 + lrow) * 72 + ks * 32 + quad * 8];
#pragma unroll
            for (int ct = 0; ct < 4; ct++)
                bfr[ct] = *(const f16x8*)&Ws[(wcol0 + ct * 16 + lrow) * 72 + ks * 32 + quad * 8];
#pragma unroll
            for (int rt = 0; rt < 4; rt++)
#pragma unroll
                for (int ct = 0; ct < 4; ct++)
                    acc[rt][ct] = __builtin_amdgcn_mfma_f32_16x16x32_f16(
                        af[rt], bfr[ct], acc[rt][ct], 0, 0, 0);
        }
        __syncthreads();
    }

    float bcol[4];
#pragma unroll
    for (int ct = 0; ct < 4; ct++) bcol[ct] = bias[wcol0 + ct * 16 + lrow];
#pragma unroll
    for (int rt = 0; rt < 4; rt++) {
#pragma unroll
        for (int ct = 0; ct < 4; ct++) {
#pragma unroll
            for (int r = 0; r < 4; r++) {
                int grow = row0 + wrow0 + rt * 16 + quad * 4 + r;
                if (grow < NN) {
                    int col = wcol0 + ct * 16 + lrow;
                    float v = fmaxf(acc[rt][ct][r] + bcol[ct], 0.f);
                    union { _Float16 h; unsigned short u; } cv;
                    cv.h = (_Float16)v;
                    outp[(size_t)grow * 128 + col] = cv.u;
                }
            }
        }
    }
}

// ---------------- SAGE L2: fused mean2-gather + GEMM ----------------
// Phase-1 computes mean2 (128 cols) for own rows -> bufQ cols 0..127 (global,
// LLC/L1-resident round-trip); __syncthreads() drains vmcnt so the block-wide
// A-stage sees it. K=256 loop identical to gemm_f16.
__launch_bounds__(256, 4)
__global__ void gemm_s2(unsigned short* __restrict__ hq,        // bufQ: h at cols 128..255
                        const int* __restrict__ row_ptr, const int* __restrict__ ecsr,
                        const unsigned short* __restrict__ Wt,   // Wt2, wld=256, K=256
                        const float* __restrict__ bias,
                        unsigned short* __restrict__ outp) {     // bufR, 128 cols
    constexpr int BM = 128;
    __shared__ unsigned short As[BM * 72];
    __shared__ unsigned short Ws[128 * 72];

    const int tid  = threadIdx.x;
    const int lane = tid & 63, wave = tid >> 6;
    const int lrow = lane & 15, quad = lane >> 4;
    const int wrow0 = (wave >> 1) * 64;
    const int wcol0 = (wave & 1) * 64;
    const int row0  = blockIdx.x * BM;

    // ---- phase 1: mean2 for own rows -> bufQ cols 0..127 ----
    {
        const int l = tid & 15;         // 16 lanes x 8 f16 = 128 cols
        const int rb = tid >> 4;        // 16 nodes per pass
#pragma unroll 1
        for (int p = 0; p < 8; p++) {
            int r = p * 16 + rb;
            int node = row0 + r;
            if (node < NN) {
                int beg = row_ptr[node], end = row_ptr[node + 1];
                float a0[8] = {0,0,0,0,0,0,0,0}, a1[8] = {0,0,0,0,0,0,0,0};
                float a2[8] = {0,0,0,0,0,0,0,0}, a3[8] = {0,0,0,0,0,0,0,0};
                int i = beg;
                for (; i + 4 <= end; i += 4) {
                    int s0 = ecsr[i], s1 = ecsr[i + 1], s2 = ecsr[i + 2], s3 = ecsr[i + 3];
                    uint4 v0 = *(const uint4*)&hq[(size_t)s0 * 256 + 128 + l * 8];
                    uint4 v1 = *(const uint4*)&hq[(size_t)s1 * 256 + 128 + l * 8];
                    uint4 v2 = *(const uint4*)&hq[(size_t)s2 * 256 + 128 + l * 8];
                    uint4 v3 = *(const uint4*)&hq[(size_t)s3 * 256 + 128 + l * 8];
                    acc8h(v0, a0); acc8h(v1, a1); acc8h(v2, a2); acc8h(v3, a3);
                }
                for (; i < end; i++) {
                    uint4 v0 = *(const uint4*)&hq[(size_t)ecsr[i] * 256 + 128 + l * 8];
                    acc8h(v0, a0);
                }
                int deg = end - beg;
                float rr = (deg > 0) ? 1.f / (float)deg : 0.f;
                union { uint4 u; _Float16 h[8]; } o;
#pragma unroll
                for (int j = 0; j < 8; j++)
                    o.h[j] = (_Float16)((a0[j] + a1[j] + a2[j] + a3[j]) * rr);
                *(uint4*)(hq + (size_t)node * 256 + l * 8) = o.u;
            }
        }
    }
    __syncthreads();   // drain vmcnt: block-wide visibility of mean2 writes

    f32x4 acc[4][4];
#pragma unroll
    for (int a = 0; a < 4; a++)
#pragma unroll
        for (int b = 0; b < 4; b++) acc[a][b] = (f32x4){0.f, 0.f, 0.f, 0.f};

#pragma unroll 1
    for (int it = 0; it < 4; ++it) {
        int base = it * 64;
        for (int t = tid; t < BM * 8; t += 256) {
            int r = t >> 3, c8 = (t & 7) * 8;
            int gr = row0 + r;
            uint4 v = make_uint4(0u, 0u, 0u, 0u);
            if (gr < NN) v = *(const uint4*)&hq[(size_t)gr * 256 + base + c8];
            *(uint4*)&As[r * 72 + c8] = v;
        }
        for (int t = tid; t < 128 * 8; t += 256) {
            int wr = t >> 3, c8 = (t & 7) * 8;
            *(uint4*)&Ws[wr * 72 + c8] = *(const uint4*)&Wt[(size_t)wr * 256 + base + c8];
        }
        __syncthreads();
#pragma unroll
        for (int ks = 0; ks < 2; ++ks) {
            f16x8 af[4], bfr[4];
#pragma unroll
            for (int rt = 0; rt < 4; rt++)
                af[rt] = *(const f16x8*)&As[(wrow0 + rt * 16 + lrow) * 72 + ks * 32 + quad * 8];
#pragma unroll
            for (int ct = 0; ct < 4; ct++)
                bfr[ct] = *(const f16x8*)&Ws[(wcol0 + ct * 16 + lrow) * 72 + ks * 32 + quad * 8];
#pragma unroll
            for (int rt = 0; rt < 4; rt++)
#pragma unroll
                for (int ct = 0; ct < 4; ct++)
                    acc[rt][ct] = __builtin_amdgcn_mfma_f32_16x16x32_f16(
                        af[rt], bfr[ct], acc[rt][ct], 0, 0, 0);
        }
        __syncthreads();
    }

    float bcol[4];
#pragma unroll
    for (int ct = 0; ct < 4; ct++) bcol[ct] = bias[wcol0 + ct * 16 + lrow];
#pragma unroll
    for (int rt = 0; rt < 4; rt++) {
#pragma unroll
        for (int ct = 0; ct < 4; ct++) {
#pragma unroll
            for (int r = 0; r < 4; r++) {
                int grow = row0 + wrow0 + rt * 16 + quad * 4 + r;
                if (grow < NN) {
                    int col = wcol0 + ct * 16 + lrow;
                    float v = fmaxf(acc[rt][ct][r] + bcol[ct], 0.f);
                    union { _Float16 h; unsigned short u; } cv;
                    cv.h = (_Float16)v;
                    outp[(size_t)grow * 128 + col] = cv.u;
                }
            }
        }
    }
}

// ---------------- launch ----------------

extern "C" void kernel_launch(void* const* d_in, const int* in_sizes, int n_in,
                              void* d_out, int out_size, void* d_ws, size_t ws_size,
                              hipStream_t stream) {
    const float* x     = (const float*)d_in[0];
    const int*   eidx  = (const int*)d_in[1];
    const float* W1l   = (const float*)d_in[2];
    const float* b1    = (const float*)d_in[3];
    const float* W1r   = (const float*)d_in[4];
    const float* Wlin1 = (const float*)d_in[5];
    const float* blin1 = (const float*)d_in[6];
    const float* W2l   = (const float*)d_in[7];
    const float* b2    = (const float*)d_in[8];
    const float* W2r   = (const float*)d_in[9];
    const float* Wlin2 = (const float*)d_in[10];
    const float* blin2 = (const float*)d_in[11];
    float* out = (float*)d_out;
    (void)in_sizes; (void)n_in; (void)out_size; (void)ws_size;

    char* ws = (char*)d_ws;
    size_t off = 0;
    auto alloc = [&](size_t bytes) -> void* {
        void* p = ws + off;
        off = (off + bytes + 255) & ~(size_t)255;
        return p;
    };
    int* bcnt    = (int*)alloc((size_t)NB * 4);
    int* bbase   = (int*)alloc((size_t)(NB + 1) * 4);
    int* bcur    = (int*)alloc((size_t)NB * 4);
    int* row_ptr = (int*)alloc((size_t)(NN + 1) * 4);
    int* ecsr    = (int*)alloc((size_t)NE * 4);
    uint2* pairs = (uint2*)alloc((size_t)NE * 8);
    unsigned short* Wt1  = (unsigned short*)alloc((size_t)128 * 128 * 2);  // [W1l|W1r]^T
    unsigned short* Wtl1 = (unsigned short*)alloc((size_t)128 * 128 * 2);  // Wlin1^T
    unsigned short* Wt2  = (unsigned short*)alloc((size_t)128 * 256 * 2);  // [W2l|W2r]^T
    unsigned short* Wtf  = (unsigned short*)alloc((size_t)64  * 128 * 2);  // Wlin2^T
    unsigned short* bufP = (unsigned short*)alloc((size_t)NN * 128 * 2);   // [unused|x] f16
    unsigned short* bufQ = (unsigned short*)alloc((size_t)NN * 256 * 2);   // [mean2|h] f16
    unsigned short* bufR = (unsigned short*)alloc((size_t)NN * 128 * 2);   // h1 / h2 f16

    // fused conversions + bcnt zeroing
    conv_fused<<<25290, 256, 0, stream>>>(x, W1l, W1r, Wlin1, W2l, W2r, Wlin2,
                                          bufP, Wt1, Wtl1, Wt2, Wtf, bcnt);

    // bucketed CSR build
    bucket_count<<<NCH, 256, 0, stream>>>(eidx, bcnt);
    bucket_scan<<<1, 512, 0, stream>>>(bcnt, bbase, bcur, row_ptr);
    bucket_scatter<<<NCH, 256, 0, stream>>>(eidx, bcur, pairs);
    bucket_csr<<<NB, 256, 0, stream>>>(pairs, bbase, row_ptr, ecsr);

    const int GB128 = (NN + 127) / 128;

    // L1 SAGE fused: mean1(own rows)->As, [mean1|x] @ [W1l;W1r] + b1, relu -> bufR
    gemm_s1<<<GB128, 256, 0, stream>>>(bufP, row_ptr, ecsr, Wt1, b1, bufR);
    // lin1: h1 @ Wlin1 + blin1, relu -> bufQ cols 128..255
    gemm_f16<128, 128, true, true><<<GB128, 256, 0, stream>>>(
        bufR, 128, Wtl1, blin1, bufQ, 256, 128, nullptr);
    // L2 SAGE fused: mean2(own rows)->bufQ cols 0..127, [mean2|h] @ [W2l;W2r] + b2, relu -> bufR
    gemm_s2<<<GB128, 256, 0, stream>>>(bufQ, row_ptr, ecsr, Wt2, b2, bufR);
    // final: h2 @ Wlin2 + blin2 -> fp32 out
    gemm_f16<128, 64, false, false><<<GB128, 256, 0, stream>>>(
        bufR, 128, Wtf, blin2, nullptr, 0, 0, out);
}

// Round 8
// 312.507 us; speedup vs baseline: 1.0567x; 1.0157x over previous
//
#include <hip/hip_runtime.h>
#include <cstddef>

static constexpr int NN = 100000;   // nodes
static constexpr int NE = 1600000;  // edges
static constexpr int NODE_SHIFT = 8;                       // 256 nodes per bucket
static constexpr int NB = (NN + 255) >> NODE_SHIFT;        // 391 buckets
static constexpr int CHUNK = 8192;                         // edges per binning block
static constexpr int NCH = (NE + CHUNK - 1) / CHUNK;       // 196 chunks

typedef _Float16 f16x8 __attribute__((ext_vector_type(8)));
typedef float f32x4  __attribute__((ext_vector_type(4)));

// accumulate 8 packed f16 (uint4) into a[0..8)
__device__ __forceinline__ void acc8h(const uint4& v, float* a) {
    union { uint4 u; _Float16 h[8]; } t; t.u = v;
#pragma unroll
    for (int j = 0; j < 8; j++) a[j] += (float)t.h[j];
}

// ---------------- bucketed CSR construction ----------------

__global__ void bucket_count(const int* __restrict__ eidx, int* __restrict__ bcnt) {
    __shared__ int h[NB];
    for (int i = threadIdx.x; i < NB; i += 256) h[i] = 0;
    __syncthreads();
    int base = blockIdx.x * CHUNK;
    int end = min(base + CHUNK, NE);
    for (int e = base + threadIdx.x; e < end; e += 256)
        atomicAdd(&h[eidx[NE + e] >> NODE_SHIFT], 1);
    __syncthreads();
    for (int i = threadIdx.x; i < NB; i += 256)
        if (h[i]) atomicAdd(&bcnt[i], h[i]);
}

__global__ void bucket_scan(const int* __restrict__ bcnt, int* __restrict__ bbase,
                            int* __restrict__ bcur, int* __restrict__ row_ptr) {
    __shared__ int s[512];
    int t = threadIdx.x;
    int v = (t < NB) ? bcnt[t] : 0;
    s[t] = v; __syncthreads();
    for (int off = 1; off < 512; off <<= 1) {
        int x = (t >= off) ? s[t - off] : 0;
        __syncthreads();
        s[t] += x;
        __syncthreads();
    }
    if (t < NB) { int e = s[t] - v; bbase[t] = e; bcur[t] = e; }
    if (t == 0) { bbase[NB] = NE; row_ptr[NN] = NE; }
}

__global__ void bucket_scatter(const int* __restrict__ eidx, int* __restrict__ bcur,
                               uint2* __restrict__ pairs) {
    __shared__ int h[NB];
    __shared__ int cur[NB];
    __shared__ int off[NB];
    for (int i = threadIdx.x; i < NB; i += 256) { h[i] = 0; cur[i] = 0; }
    __syncthreads();
    int base = blockIdx.x * CHUNK;
    int end = min(base + CHUNK, NE);
    for (int e = base + threadIdx.x; e < end; e += 256)
        atomicAdd(&h[eidx[NE + e] >> NODE_SHIFT], 1);
    __syncthreads();
    for (int i = threadIdx.x; i < NB; i += 256)
        off[i] = h[i] ? atomicAdd(&bcur[i], h[i]) : 0;
    __syncthreads();
    for (int e = base + threadIdx.x; e < end; e += 256) {
        int d = eidx[NE + e], s = eidx[e];
        int b = d >> NODE_SHIFT;
        int p = atomicAdd(&cur[b], 1);
        pairs[off[b] + p] = make_uint2((unsigned)s, (unsigned)d);
    }
}

__launch_bounds__(256)
__global__ void bucket_csr(const uint2* __restrict__ pairs, const int* __restrict__ bbase,
                           int* __restrict__ row_ptr, int* __restrict__ ecsr) {
    __shared__ int hist[256];
    __shared__ int scn[256];
    __shared__ int cur[256];
    int b = blockIdx.x, t = threadIdx.x;
    int ebeg = bbase[b], eend = bbase[b + 1];
    int node0 = b << NODE_SHIFT;
    hist[t] = 0;
    __syncthreads();
    for (int e = ebeg + t; e < eend; e += 256)
        atomicAdd(&hist[pairs[e].y & 255u], 1);
    __syncthreads();
    int v = hist[t];
    scn[t] = v; __syncthreads();
    for (int off = 1; off < 256; off <<= 1) {
        int x = (t >= off) ? scn[t - off] : 0;
        __syncthreads();
        scn[t] += x;
        __syncthreads();
    }
    int excl = scn[t] - v;
    int node = node0 + t;
    if (node < NN) row_ptr[node] = ebeg + excl;
    cur[t] = excl;
    __syncthreads();
    for (int e = ebeg + t; e < eend; e += 256) {
        uint2 pr = pairs[e];
        int p = atomicAdd(&cur[pr.y & 255u], 1);
        ecsr[ebeg + p] = (int)pr.x;
    }
}

// ---------------- fused conversions + bcnt zeroing (one launch) ----------------
// blocks [0,25000): x -> f16 bufP cols [64,128)
// blocks [25000,25288): the six W -> Wt^T f16 conversions
// blocks [25288,25290): zero bcnt
__global__ void conv_fused(const float* __restrict__ x,
                           const float* __restrict__ W1l, const float* __restrict__ W1r,
                           const float* __restrict__ Wlin1, const float* __restrict__ W2l,
                           const float* __restrict__ W2r, const float* __restrict__ Wlin2,
                           unsigned short* __restrict__ bufP, unsigned short* __restrict__ Wt1,
                           unsigned short* __restrict__ Wtl1, unsigned short* __restrict__ Wt2,
                           unsigned short* __restrict__ Wtf, int* __restrict__ bcnt) {
    int bid = blockIdx.x, t = threadIdx.x;
    union { _Float16 h; unsigned short u; } cv;
    if (bid < 25000) {
        int idx = bid * 256 + t;               // < NN*64 = 6.4M exactly
        int r = idx >> 6, c = idx & 63;
        cv.h = (_Float16)x[idx];
        bufP[(size_t)r * 128 + 64 + c] = cv.u;
    } else if (bid >= 25288) {
        int i = (bid - 25288) * 256 + t;
        if (i < NB) bcnt[i] = 0;
    } else {
        int b = bid - 25000;
        const float* W; unsigned short* Wt; int K, C, wld, kbase, base;
        if (b < 32)       { W = W1l;   Wt = Wt1;  K = 64;  C = 128; wld = 128; kbase = 0;   base = b; }
        else if (b < 64)  { W = W1r;   Wt = Wt1;  K = 64;  C = 128; wld = 128; kbase = 64;  base = b - 32; }
        else if (b < 128) { W = Wlin1; Wt = Wtl1; K = 128; C = 128; wld = 128; kbase = 0;   base = b - 64; }
        else if (b < 192) { W = W2l;   Wt = Wt2;  K = 128; C = 128; wld = 256; kbase = 0;   base = b - 128; }
        else if (b < 256) { W = W2r;   Wt = Wt2;  K = 128; C = 128; wld = 256; kbase = 128; base = b - 192; }
        else              { W = Wlin2; Wt = Wtf;  K = 128; C = 64;  wld = 128; kbase = 0;   base = b - 256; }
        int idx = base * 256 + t;
        if (idx < K * C) {
            int k = idx / C, c = idx % C;
            cv.h = (_Float16)W[idx];
            Wt[(size_t)c * wld + kbase + k] = cv.u;
        }
    }
}

// ---------------- mean aggregation (f16 gather, 16B/lane, x4 unroll) ----------------
// Rounds 12-17 post-mortems: wave rebalance (-), MLP 4->8 (flat on agg2, - on agg1),
// fuse-into-GEMM (- : grid-capped TLP). This x4 / 4-acc / VGPR-40 TPN form is the
// measured optimum; agg2 sits at the random-256B-granule service-rate floor
// (44% apparent HBM, 0 bank conflicts, all three levers exhausted).

// layer 1: gather f16 x rows (bufP cols [64,128), 128B), mean -> bufP cols [0,64)
__launch_bounds__(256)
__global__ void agg1(const unsigned short* __restrict__ xp, const int* __restrict__ row_ptr,
                     const int* __restrict__ ecsr, unsigned short* __restrict__ outp) {
    constexpr int TPN = 8;
    int node = blockIdx.x * (256 / TPN) + threadIdx.x / TPN;
    int lane = threadIdx.x % TPN;
    if (node >= NN) return;
    int beg = row_ptr[node], end = row_ptr[node + 1];

    float a0[8] = {0,0,0,0,0,0,0,0}, a1[8] = {0,0,0,0,0,0,0,0};
    float a2[8] = {0,0,0,0,0,0,0,0}, a3[8] = {0,0,0,0,0,0,0,0};
    int i = beg;
    for (; i + 4 <= end; i += 4) {
        int s0 = ecsr[i], s1 = ecsr[i + 1], s2 = ecsr[i + 2], s3 = ecsr[i + 3];
        uint4 v0 = *(const uint4*)&xp[(size_t)s0 * 128 + 64 + lane * 8];
        uint4 v1 = *(const uint4*)&xp[(size_t)s1 * 128 + 64 + lane * 8];
        uint4 v2 = *(const uint4*)&xp[(size_t)s2 * 128 + 64 + lane * 8];
        uint4 v3 = *(const uint4*)&xp[(size_t)s3 * 128 + 64 + lane * 8];
        acc8h(v0, a0); acc8h(v1, a1); acc8h(v2, a2); acc8h(v3, a3);
    }
    for (; i < end; i++) {
        uint4 v0 = *(const uint4*)&xp[(size_t)ecsr[i] * 128 + 64 + lane * 8];
        acc8h(v0, a0);
    }
    int deg = end - beg;
    float r = (deg > 0) ? 1.f / (float)deg : 0.f;
    union { uint4 u; _Float16 h[8]; } o;
#pragma unroll
    for (int j = 0; j < 8; j++)
        o.h[j] = (_Float16)((a0[j] + a1[j] + a2[j] + a3[j]) * r);
    *(uint4*)(outp + (size_t)node * 128 + lane * 8) = o.u;
}

// layer 2: gather f16 h rows (bufQ cols [128,256), 256B), mean -> bufQ cols [0,128)
__launch_bounds__(256)
__global__ void agg2(const unsigned short* __restrict__ hbuf, const int* __restrict__ row_ptr,
                     const int* __restrict__ ecsr, unsigned short* __restrict__ outp) {
    constexpr int TPN = 16;
    int node = blockIdx.x * (256 / TPN) + threadIdx.x / TPN;
    int lane = threadIdx.x % TPN;
    if (node >= NN) return;
    int beg = row_ptr[node], end = row_ptr[node + 1];

    float a0[8] = {0,0,0,0,0,0,0,0}, a1[8] = {0,0,0,0,0,0,0,0};
    float a2[8] = {0,0,0,0,0,0,0,0}, a3[8] = {0,0,0,0,0,0,0,0};
    int i = beg;
    for (; i + 4 <= end; i += 4) {
        int s0 = ecsr[i], s1 = ecsr[i + 1], s2 = ecsr[i + 2], s3 = ecsr[i + 3];
        uint4 v0 = *(const uint4*)&hbuf[(size_t)s0 * 256 + 128 + lane * 8];
        uint4 v1 = *(const uint4*)&hbuf[(size_t)s1 * 256 + 128 + lane * 8];
        uint4 v2 = *(const uint4*)&hbuf[(size_t)s2 * 256 + 128 + lane * 8];
        uint4 v3 = *(const uint4*)&hbuf[(size_t)s3 * 256 + 128 + lane * 8];
        acc8h(v0, a0); acc8h(v1, a1); acc8h(v2, a2); acc8h(v3, a3);
    }
    for (; i < end; i++) {
        uint4 v0 = *(const uint4*)&hbuf[(size_t)ecsr[i] * 256 + 128 + lane * 8];
        acc8h(v0, a0);
    }
    int deg = end - beg;
    float r = (deg > 0) ? 1.f / (float)deg : 0.f;
    union { uint4 u; _Float16 h[8]; } o;
#pragma unroll
    for (int j = 0; j < 8; j++)
        o.h[j] = (_Float16)((a0[j] + a1[j] + a2[j] + a3[j]) * r);
    *(uint4*)(outp + (size_t)node * 256 + lane * 8) = o.u;
}

// ---------------- single-pass f16 MFMA GEMM (round-9 structure) ----------------
template<int K, int C, bool RELU, bool F16OUT>
__launch_bounds__(256, 4)
__global__ void gemm_f16(const unsigned short* __restrict__ A, int lda,
                         const unsigned short* __restrict__ Wt,
                         const float* __restrict__ bias,
                         unsigned short* __restrict__ outp, int old_, int obase,
                         float* __restrict__ outf) {
    constexpr int BM  = 128;
    constexpr int NKC = K / 64;
    constexpr int RT  = (C == 128) ? 4 : 2;
    __shared__ unsigned short As[BM * 72];
    __shared__ unsigned short Ws[C * 72];

    const int tid  = threadIdx.x;
    const int lane = tid & 63, wave = tid >> 6;
    const int lrow = lane & 15, quad = lane >> 4;
    const int wrow0 = (C == 128) ? (wave >> 1) * 64 : wave * 32;
    const int wcol0 = (C == 128) ? (wave & 1) * 64 : 0;
    const int row0  = blockIdx.x * BM;

    f32x4 acc[RT][4];
#pragma unroll
    for (int a = 0; a < RT; a++)
#pragma unroll
        for (int b = 0; b < 4; b++) acc[a][b] = (f32x4){0.f, 0.f, 0.f, 0.f};

#pragma unroll 1
    for (int it = 0; it < NKC; ++it) {
        int base = it * 64;
        for (int t = tid; t < BM * 8; t += 256) {
            int r = t >> 3, c8 = (t & 7) * 8;
            int gr = row0 + r;
            uint4 v = make_uint4(0u, 0u, 0u, 0u);
            if (gr < NN) v = *(const uint4*)&A[(size_t)gr * lda + base + c8];
            *(uint4*)&As[r * 72 + c8] = v;
        }
        for (int t = tid; t < C * 8; t += 256) {
            int wr = t >> 3, c8 = (t & 7) * 8;
            *(uint4*)&Ws[wr * 72 + c8] = *(const uint4*)&Wt[(size_t)wr * K + base + c8];
        }
        __syncthreads();
#pragma unroll
        for (int ks = 0; ks < 2; ++ks) {
            f16x8 af[RT], bfr[4];
#pragma unroll
            for (int rt = 0; rt < RT; rt++)
                af[rt] = *(const f16x8*)&As[(wrow0 + rt * 16 + lrow) * 72 + ks * 32 + quad * 8];
#pragma unroll
            for (int ct = 0; ct < 4; ct++)
                bfr[ct] = *(const f16x8*)&Ws[(wcol0 + ct * 16 + lrow) * 72 + ks * 32 + quad * 8];
#pragma unroll
            for (int rt = 0; rt < RT; rt++)
#pragma unroll
                for (int ct = 0; ct < 4; ct++)
                    acc[rt][ct] = __builtin_amdgcn_mfma_f32_16x16x32_f16(
                        af[rt], bfr[ct], acc[rt][ct], 0, 0, 0);
        }
        __syncthreads();
    }

    // epilogue: C/D layout col=lane&15, row=quad*4+reg [m89/m91 verified]
    float bcol[4];
#pragma unroll
    for (int ct = 0; ct < 4; ct++) bcol[ct] = bias[wcol0 + ct * 16 + lrow];
#pragma unroll
    for (int rt = 0; rt < RT; rt++) {
#pragma unroll
        for (int ct = 0; ct < 4; ct++) {
#pragma unroll
            for (int r = 0; r < 4; r++) {
                int grow = row0 + wrow0 + rt * 16 + quad * 4 + r;
                if (grow < NN) {
                    int col = wcol0 + ct * 16 + lrow;
                    float v = acc[rt][ct][r] + bcol[ct];
                    if (RELU) v = fmaxf(v, 0.f);
                    if (F16OUT) {
                        union { _Float16 h; unsigned short u; } cv;
                        cv.h = (_Float16)v;
                        outp[(size_t)grow * old_ + obase + col] = cv.u;
                    } else {
                        outf[(size_t)grow * C + col] = v;
                    }
                }
            }
        }
    }
}

// ---------------- launch ----------------

extern "C" void kernel_launch(void* const* d_in, const int* in_sizes, int n_in,
                              void* d_out, int out_size, void* d_ws, size_t ws_size,
                              hipStream_t stream) {
    const float* x     = (const float*)d_in[0];
    const int*   eidx  = (const int*)d_in[1];
    const float* W1l   = (const float*)d_in[2];
    const float* b1    = (const float*)d_in[3];
    const float* W1r   = (const float*)d_in[4];
    const float* Wlin1 = (const float*)d_in[5];
    const float* blin1 = (const float*)d_in[6];
    const float* W2l   = (const float*)d_in[7];
    const float* b2    = (const float*)d_in[8];
    const float* W2r   = (const float*)d_in[9];
    const float* Wlin2 = (const float*)d_in[10];
    const float* blin2 = (const float*)d_in[11];
    float* out = (float*)d_out;
    (void)in_sizes; (void)n_in; (void)out_size; (void)ws_size;

    char* ws = (char*)d_ws;
    size_t off = 0;
    auto alloc = [&](size_t bytes) -> void* {
        void* p = ws + off;
        off = (off + bytes + 255) & ~(size_t)255;
        return p;
    };
    int* bcnt    = (int*)alloc((size_t)NB * 4);
    int* bbase   = (int*)alloc((size_t)(NB + 1) * 4);
    int* bcur    = (int*)alloc((size_t)NB * 4);
    int* row_ptr = (int*)alloc((size_t)(NN + 1) * 4);
    int* ecsr    = (int*)alloc((size_t)NE * 4);
    uint2* pairs = (uint2*)alloc((size_t)NE * 8);
    unsigned short* Wt1  = (unsigned short*)alloc((size_t)128 * 128 * 2);  // [W1l|W1r]^T
    unsigned short* Wtl1 = (unsigned short*)alloc((size_t)128 * 128 * 2);  // Wlin1^T
    unsigned short* Wt2  = (unsigned short*)alloc((size_t)128 * 256 * 2);  // [W2l|W2r]^T
    unsigned short* Wtf  = (unsigned short*)alloc((size_t)64  * 128 * 2);  // Wlin2^T
    unsigned short* bufP = (unsigned short*)alloc((size_t)NN * 128 * 2);   // [mean1|x] f16
    unsigned short* bufQ = (unsigned short*)alloc((size_t)NN * 256 * 2);   // [mean2|h] f16
    unsigned short* bufR = (unsigned short*)alloc((size_t)NN * 128 * 2);   // h1 / h2 f16

    // fused conversions + bcnt zeroing (1 launch replaces 8)
    conv_fused<<<25290, 256, 0, stream>>>(x, W1l, W1r, Wlin1, W2l, W2r, Wlin2,
                                          bufP, Wt1, Wtl1, Wt2, Wtf, bcnt);

    // bucketed CSR build
    bucket_count<<<NCH, 256, 0, stream>>>(eidx, bcnt);
    bucket_scan<<<1, 512, 0, stream>>>(bcnt, bbase, bcur, row_ptr);
    bucket_scatter<<<NCH, 256, 0, stream>>>(eidx, bcur, pairs);
    bucket_csr<<<NB, 256, 0, stream>>>(pairs, bbase, row_ptr, ecsr);

    // mean1 -> bufP cols 0..63
    agg1<<<(NN + 31) / 32, 256, 0, stream>>>(bufP, row_ptr, ecsr, bufP);

    const int GB128 = (NN + 127) / 128;

    // L1 SAGE: bufP[mean1|x] @ [W1l;W1r] + b1, relu -> h1 (bufR)
    gemm_f16<128, 128, true, true><<<GB128, 256, 0, stream>>>(
        bufP, 128, Wt1, b1, bufR, 128, 0, nullptr);
    // lin1: h1 @ Wlin1 + blin1, relu -> h (bufQ cols 128..255)
    gemm_f16<128, 128, true, true><<<GB128, 256, 0, stream>>>(
        bufR, 128, Wtl1, blin1, bufQ, 256, 128, nullptr);
    // mean2 from h -> bufQ cols 0..127
    agg2<<<(NN + 15) / 16, 256, 0, stream>>>(bufQ, row_ptr, ecsr, bufQ);
    // L2 SAGE: bufQ[mean2|h] @ [W2l;W2r] + b2, relu -> h2 (bufR)
    gemm_f16<256, 128, true, true><<<GB128, 256, 0, stream>>>(
        bufQ, 256, Wt2, b2, bufR, 128, 0, nullptr);
    // final: h2 @ Wlin2 + blin2 -> fp32 out
    gemm_f16<128, 64, false, false><<<GB128, 256, 0, stream>>>(
        bufR, 128, Wtf, blin2, nullptr, 0, 0, out);
}